// Round 1
// 151.819 us; speedup vs baseline: 1.3784x; 1.3784x over previous
//
#include <hip/hip_runtime.h>
#include <stdint.h>

// Problem constants (match reference)
#define BATCH    256
#define MPTS     512
#define KNN      33
#define RADIUS_F 5.0f
#define EDGES    (BATCH * MPTS * KNN)   // 4,325,376 edges; out = 4*EDGES float32

#define BLOCKS_PER_GRAPH 8
#define ROWS_PER_BLOCK   64             // MPTS / BLOCKS_PER_GRAPH
#define THREADS          256
#define WAVES_PER_BLOCK  4              // THREADS / 64
#define CAP              128            // survivor capacity (64 fast path, 128 fallback)
#define SLOT_STRIDE      (CAP + 2)      // +1 dump slot, +1 pad

// ---------------------------------------------------------------------------
// Cross-lane xor-shuffle: J in {1,2,8} via DPP (quad_perm / row_ror:8),
// J in {4,16} via ds_swizzle BitMode xor, J==32 via shfl (crosses 32-halves).
template <int J>
static __device__ __forceinline__ uint32_t shx32(uint32_t x) {
    if constexpr (J == 1)
        return (uint32_t)__builtin_amdgcn_update_dpp(0, (int)x, 0xB1, 0xF, 0xF, false);  // quad_perm [1,0,3,2]
    else if constexpr (J == 2)
        return (uint32_t)__builtin_amdgcn_update_dpp(0, (int)x, 0x4E, 0xF, 0xF, false);  // quad_perm [2,3,0,1]
    else if constexpr (J == 8)
        return (uint32_t)__builtin_amdgcn_update_dpp(0, (int)x, 0x128, 0xF, 0xF, false); // row_ror:8 == xor8 in 16
    else if constexpr (J == 4)
        return (uint32_t)__builtin_amdgcn_ds_swizzle((int)x, 0x101F);                    // xor4
    else if constexpr (J == 16)
        return (uint32_t)__builtin_amdgcn_ds_swizzle((int)x, 0x401F);                    // xor16
    else
        return (uint32_t)__shfl_xor((int)x, 32, 64);                                     // xor32
}

template <int J>
static __device__ __forceinline__ uint64_t shx64(uint64_t v) {
    const uint32_t lo = shx32<J>((uint32_t)v);
    const uint32_t hi = shx32<J>((uint32_t)(v >> 32));
    return ((uint64_t)hi << 32) | (uint64_t)lo;
}

// One bitonic compare-exchange stage at distance J. lowJ = ((idx&J)==0),
// up = ((idx&K)==0). Bools live as wave masks -> km / (cv==km) are SALU ops;
// VALU cost per CE: 2 shuffles + v_cmp_lt_u64 + 2 cndmask.
template <int J>
static __device__ __forceinline__ void ce_s(uint64_t& v, bool lowJ, bool up) {
    const uint64_t p = shx64<J>(v);
    const bool km = (lowJ == up);      // this element keeps the min of the pair
    v = ((v < p) == km) ? v : p;
}

// Full ascending bitonic sort of 64 u64 keys, one per lane.
static __device__ __forceinline__ uint64_t bsort64(uint64_t v,
        bool b1, bool b2, bool b4, bool b8, bool b16, bool b32) {
    ce_s<1>(v, b1, b2);
    ce_s<2>(v, b2, b4);   ce_s<1>(v, b1, b4);
    ce_s<4>(v, b4, b8);   ce_s<2>(v, b2, b8);   ce_s<1>(v, b1, b8);
    ce_s<8>(v, b8, b16);  ce_s<4>(v, b4, b16);  ce_s<2>(v, b2, b16);  ce_s<1>(v, b1, b16);
    ce_s<16>(v, b16, b32); ce_s<8>(v, b8, b32); ce_s<4>(v, b4, b32);  ce_s<2>(v, b2, b32); ce_s<1>(v, b1, b32);
    ce_s<32>(v, b32, true); ce_s<16>(v, b16, true); ce_s<8>(v, b8, true);
    ce_s<4>(v, b4, true);   ce_s<2>(v, b2, true);   ce_s<1>(v, b1, true);
    return v;
}

// Ascending bitonic sort of 128 u64 keys: v0 = element lane, v1 = element 64+lane.
static __device__ __forceinline__ void bsort128(uint64_t& v0, uint64_t& v1,
        bool b1, bool b2, bool b4, bool b8, bool b16, bool b32) {
    // levels K=2..32: identical pattern for both regs ((idx&K) == (lane&K))
    ce_s<1>(v0, b1, b2);   ce_s<1>(v1, b1, b2);
    ce_s<2>(v0, b2, b4);   ce_s<2>(v1, b2, b4);   ce_s<1>(v0, b1, b4);   ce_s<1>(v1, b1, b4);
    ce_s<4>(v0, b4, b8);   ce_s<4>(v1, b4, b8);   ce_s<2>(v0, b2, b8);   ce_s<2>(v1, b2, b8);
    ce_s<1>(v0, b1, b8);   ce_s<1>(v1, b1, b8);
    ce_s<8>(v0, b8, b16);  ce_s<8>(v1, b8, b16);  ce_s<4>(v0, b4, b16);  ce_s<4>(v1, b4, b16);
    ce_s<2>(v0, b2, b16);  ce_s<2>(v1, b2, b16);  ce_s<1>(v0, b1, b16);  ce_s<1>(v1, b1, b16);
    ce_s<16>(v0, b16, b32); ce_s<16>(v1, b16, b32); ce_s<8>(v0, b8, b32); ce_s<8>(v1, b8, b32);
    ce_s<4>(v0, b4, b32);   ce_s<4>(v1, b4, b32);   ce_s<2>(v0, b2, b32); ce_s<2>(v1, b2, b32);
    ce_s<1>(v0, b1, b32);   ce_s<1>(v1, b1, b32);
    // level K=64: reg0 ascending ((idx&64)==0), reg1 descending
    ce_s<32>(v0, b32, true); ce_s<32>(v1, b32, false);
    ce_s<16>(v0, b16, true); ce_s<16>(v1, b16, false);
    ce_s<8>(v0, b8, true);   ce_s<8>(v1, b8, false);
    ce_s<4>(v0, b4, true);   ce_s<4>(v1, b4, false);
    ce_s<2>(v0, b2, true);   ce_s<2>(v1, b2, false);
    ce_s<1>(v0, b1, true);   ce_s<1>(v1, b1, false);
    // level K=128: j=64 is the cross-reg CE (always ascending), then j=32..1
    {
        const bool sw = (v1 < v0);
        const uint64_t a = sw ? v1 : v0;
        const uint64_t b = sw ? v0 : v1;
        v0 = a; v1 = b;
    }
    ce_s<32>(v0, b32, true); ce_s<32>(v1, b32, true);
    ce_s<16>(v0, b16, true); ce_s<16>(v1, b16, true);
    ce_s<8>(v0, b8, true);   ce_s<8>(v1, b8, true);
    ce_s<4>(v0, b4, true);   ce_s<4>(v1, b4, true);
    ce_s<2>(v0, b2, true);   ce_s<2>(v1, b2, true);
    ce_s<1>(v0, b1, true);   ce_s<1>(v1, b1, true);
}

// Wave-wide inclusive scan (classic GCN DPP ladder: shr1/2/4/8, bcast15, bcast31).
static __device__ __forceinline__ uint32_t wave_incl_scan(uint32_t x) {
    x += (uint32_t)__builtin_amdgcn_update_dpp(0, (int)x, 0x111, 0xF, 0xF, false);
    x += (uint32_t)__builtin_amdgcn_update_dpp(0, (int)x, 0x112, 0xF, 0xF, false);
    x += (uint32_t)__builtin_amdgcn_update_dpp(0, (int)x, 0x114, 0xF, 0xF, false);
    x += (uint32_t)__builtin_amdgcn_update_dpp(0, (int)x, 0x118, 0xF, 0xF, false);
    x += (uint32_t)__builtin_amdgcn_update_dpp(0, (int)x, 0x142, 0xA, 0xF, false);
    x += (uint32_t)__builtin_amdgcn_update_dpp(0, (int)x, 0x143, 0xC, 0xF, false);
    return x;
}

__global__ void __launch_bounds__(THREADS)
InteractionModule_50483045597845_kernel(const float* __restrict__ pos,
                                        float* __restrict__ out) {
    // 8 KB: one graph's 512 points as (x, y, z, |p|^2)
    __shared__ float4 spt[MPTS];
    // 8.1 KB: per-(wave,row) survivor slots, u64 = (key << 32) | n.
    __shared__ uint64_t slots[WAVES_PER_BLOCK * 2][SLOT_STRIDE];

    const int graph = blockIdx.x / BLOCKS_PER_GRAPH;
    const int slice = blockIdx.x - graph * BLOCKS_PER_GRAPH;
    const int tid   = (int)threadIdx.x;

    for (int p = tid; p < MPTS; p += THREADS) {
        const float* pp = pos + (size_t)(graph * MPTS + p) * 3;
        const float x = pp[0], y = pp[1], z = pp[2];
        // fma-chain |p|^2 — matches dot() below exactly so self-edge d2 == 0
        const float sq = __builtin_fmaf(x, x, __builtin_fmaf(y, y, __fmul_rn(z, z)));
        spt[p] = make_float4(x, y, z, sq);
    }
    __syncthreads();

    const int lane = tid & 63;
    const int wave = tid >> 6;

    // hoisted lane-bit predicates for the bitonic networks (live as sgpr masks)
    const bool b1  = (lane & 1) == 0;
    const bool b2  = (lane & 2) == 0;
    const bool b4  = (lane & 4) == 0;
    const bool b8  = (lane & 8) == 0;
    const bool b16 = (lane & 16) == 0;
    const bool b32 = (lane & 32) == 0;

    // Pivot-select + compact + one cross-lane bitonic sort, per row.
    // Sort key u64 = (key << 32) | n orders by (trunc-d2, j, lane) == (d2, n):
    // exactly the tournament/top_k tie-break order. Self edge (d2==0) is the
    // natural global min — no special-casing.
    auto doRow = [&](const uint32_t* sk, const float4 pc, int mRow, int region) {
        // per-lane head (min of its 8 keys)
        uint32_t h = sk[0];
        #pragma unroll
        for (int j = 1; j < 8; ++j) h = sk[j] < h ? sk[j] : h;

        // Bisect pivot P on HEAD count: headcount(<=P) >= 33 implies
        // elementcount(<=P) >= 33 (each such head is itself an element).
        // Early-exit window [33,36] keeps E[survivors] ~ 46.
        uint32_t blo = 0u, bhi = 0x7FFFFFFFu;
        while (blo < bhi) {
            const uint32_t mid = (blo + bhi) >> 1;
            const int c = __popcll(__ballot(h <= mid));
            if (c < KNN) blo = mid + 1;
            else { bhi = mid; if (c <= KNN + 3) break; }
        }
        uint32_t P = bhi;

        uint32_t cnt = 0;
        #pragma unroll
        for (int j = 0; j < 8; ++j) cnt += (sk[j] <= P) ? 1u : 0u;
        uint32_t incl  = wave_incl_scan(cnt);
        uint32_t total = (uint32_t)__builtin_amdgcn_readlane((int)incl, 63);

        if (total > 64u) {
            // rare (~4%): refine to the exact minimal valid pivot, recount
            while (blo < bhi) {
                const uint32_t mid = (blo + bhi) >> 1;
                const int c = __popcll(__ballot(h <= mid));
                if (c < KNN) blo = mid + 1; else bhi = mid;
            }
            P = bhi;
            cnt = 0;
            #pragma unroll
            for (int j = 0; j < 8; ++j) cnt += (sk[j] <= P) ? 1u : 0u;
            incl  = wave_incl_scan(cnt);
            total = (uint32_t)__builtin_amdgcn_readlane((int)incl, 63);
            // total > 128 would need >128 elements tied at the minimal pivot
            // (~9-sigma on this data); such survivors are capped to the dump slot.
        }
        uint32_t dest = incl - cnt;   // exclusive base for this lane's survivors

        slots[region][lane]      = ~0ull;   // +INF padding sorts to the tail
        slots[region][64 + lane] = ~0ull;

        #pragma unroll
        for (int j = 0; j < 8; ++j) {
            const bool     surv = (sk[j] <= P);
            const uint32_t d    = (surv && dest < (uint32_t)CAP) ? dest : (uint32_t)CAP;
            slots[region][d]    = ((uint64_t)sk[j] << 32) | (uint32_t)(lane | (j << 6));
            dest += surv ? 1u : 0u;
        }

        // same-wave producer/consumer: lgkmcnt ordering only, no barrier
        uint64_t v0 = slots[region][lane];
        if (total <= 64u) {
            v0 = bsort64(v0, b1, b2, b4, b8, b16, b32);
        } else {
            uint64_t v1 = slots[region][64 + lane];
            bsort128(v0, v1, b1, b2, b4, b8, b16, b32);
        }

        // Epilogue: lane k holds the k-th neighbor. dist/mask recomputed
        // exactly as numpy fp32 (rn ops, same order) — bit-identical given
        // identical (src,dst).
        if (lane < KNN) {
            const int kept  = (int)((uint32_t)v0 & 0x1FFu);
            const float4 q  = spt[kept];
            const float dx  = __fsub_rn(q.x, pc.x);
            const float dy  = __fsub_rn(q.y, pc.y);
            const float dz  = __fsub_rn(q.z, pc.z);
            const float ss  = __fadd_rn(__fadd_rn(__fmul_rn(dx, dx),
                                                  __fmul_rn(dy, dy)),
                                        __fmul_rn(dz, dz));
            const float dist  = (ss > 0.0f) ? __fsqrt_rn(ss) : 0.0f;
            const float maskv = (dist <= RADIUS_F) ? 1.0f : 0.0f;
            const size_t e    = (size_t)mRow * KNN + (size_t)lane;
            out[e]                     = (float)(graph * MPTS + kept);
            out[(size_t)EDGES + e]     = (float)mRow;
            out[2 * (size_t)EDGES + e] = dist;
            out[3 * (size_t)EDGES + e] = maskv;
        }
    };

    // 8 outer iterations × (4 waves × 2 rows) = 64 rows per block.
    #pragma unroll 1
    for (int it = 0; it < ROWS_PER_BLOCK / (WAVES_PER_BLOCK * 2); ++it) {
        const int mA = slice * ROWS_PER_BLOCK + it * (WAVES_PER_BLOCK * 2) + wave;
        const int mB = mA + WAVES_PER_BLOCK;

        const float4 pa = spt[mA];
        const float4 pb = spt[mB];

        // Lane holds candidates n = lane + 64*j for BOTH rows (shared q load).
        // 32-bit key = (d2bits & ~7) | j; 8-ulp truncation perturbs only
        // near-exact ties (dist recomputed exactly).
        uint32_t sA[8], sB[8];
        #pragma unroll
        for (int j = 0; j < 8; ++j) {
            const int n = lane + (j << 6);
            const float4 q = spt[n];
            const float dotA = __builtin_fmaf(pa.x, q.x,
                               __builtin_fmaf(pa.y, q.y, __fmul_rn(pa.z, q.z)));
            const float dotB = __builtin_fmaf(pb.x, q.x,
                               __builtin_fmaf(pb.y, q.y, __fmul_rn(pb.z, q.z)));
            float d2A = __builtin_fmaf(-2.0f, dotA, __fadd_rn(pa.w, q.w));
            float d2B = __builtin_fmaf(-2.0f, dotB, __fadd_rn(pb.w, q.w));
            d2A = fmaxf(d2A, 0.0f);
            d2B = fmaxf(d2B, 0.0f);
            sA[j] = (__float_as_uint(d2A) & 0xFFFFFFF8u) | (uint32_t)j;
            sB[j] = (__float_as_uint(d2B) & 0xFFFFFFF8u) | (uint32_t)j;
        }

        doRow(sA, pa, graph * MPTS + mA, wave);
        doRow(sB, pb, graph * MPTS + mB, wave + WAVES_PER_BLOCK);
    }
}

extern "C" void kernel_launch(void* const* d_in, const int* in_sizes, int n_in,
                              void* d_out, int out_size, void* d_ws, size_t ws_size,
                              hipStream_t stream) {
    (void)in_sizes; (void)n_in; (void)out_size; (void)d_ws; (void)ws_size;
    const float* pos = (const float*)d_in[0];   // d_in[1] (batch) implied by layout
    float*       out = (float*)d_out;
    hipLaunchKernelGGL(InteractionModule_50483045597845_kernel,
                       dim3(BATCH * BLOCKS_PER_GRAPH), dim3(THREADS), 0, stream,
                       pos, out);
}